// Round 1
// baseline (459.276 us; speedup 1.0000x reference)
//
#include <hip/hip_runtime.h>

#define Bn 256
#define Dk 2048
#define Cc 8
#define Mm 2048
#define Nn 16384
#define BG 50
#define INV_T 20.0f

typedef __attribute__((ext_vector_type(8))) short bf16x8;
typedef __attribute__((ext_vector_type(4))) float f32x4;

__device__ inline short f2bf(float f) {
  unsigned u = __builtin_bit_cast(unsigned, f);
  u = (u + 0x7fffu + ((u >> 16) & 1u)) >> 16;   // RNE, inputs finite
  return (short)u;
}
// order-isomorphic mapping float -> uint (monotone for all finite values)
__device__ inline unsigned f2ord(float f) {
  unsigned u = __builtin_bit_cast(unsigned, f);
  return (u & 0x80000000u) ? ~u : (u | 0x80000000u);
}
__device__ inline float ord2f(unsigned o) {
  unsigned u = (o & 0x80000000u) ? (o ^ 0x80000000u) : ~o;
  return __builtin_bit_cast(float, u);
}

// ---------------------------------------------------------------- prep: cam histogram, first-occurrence flags
__global__ __launch_bounds__(256) void prep_kernel(const int* __restrict__ cams,
                                                   const int* __restrict__ targets,
                                                   int* __restrict__ cnt,
                                                   int* __restrict__ rowArr,
                                                   int* __restrict__ first) {
  __shared__ int rs[Bn];
  __shared__ int lc[Cc];
  const int t = threadIdx.x;
  const int r = cams[t] * Mm + targets[t];
  rs[t] = r;
  if (t < Cc) lc[t] = 0;
  __syncthreads();
  atomicAdd(&lc[cams[t]], 1);
  __syncthreads();
  if (t < Cc) cnt[t] = lc[t];
  int fst = 1;
  for (int j = 0; j < t; ++j)
    if (rs[j] == r) fst = 0;
  rowArr[t] = r;
  first[t] = fst;
}

// ---------------------------------------------------------------- convert+pack A: f32 -> bf16, per-K-tile (BK=32) layout
// aPack[kt][row][k] : kt in [0,64), row in [0,256), k in [0,32)  => staging loads are lane-contiguous
__global__ __launch_bounds__(256) void convert_kernel(const float* __restrict__ x,
                                                      short* __restrict__ a, int n4) {
  int i = blockIdx.x * 256 + threadIdx.x;
  if (i >= n4) return;
  float4 v = ((const float4*)x)[i];
  int row = i >> 9, j = i & 511;          // 512 float4 per row
  int kt = j >> 3, off = (j & 7) * 4;     // 8 float4 per K-tile of 32
  short4 h;
  h.x = f2bf(v.x); h.y = f2bf(v.y); h.z = f2bf(v.z); h.w = f2bf(v.w);
  *(short4*)(a + (size_t)kt * (Bn * 32) + row * 32 + off) = h;
}

// ---------------------------------------------------------------- GEMM sims = A @ em^T, fused em copy-out
// BM=256, BN=64, BK=32, 512 threads (8 waves), grid 256, double-buffered LDS, 1 barrier/iter
// DEPTH-deep register prefetch queue: keeps 3 K-tiles of Em (24 KB/CU) in flight
// across barriers -> covers ~1000cy HBM latency at the CU's 10 B/cy HBM share.
#define SA 40       // LDS row stride in shorts (32 + 8 pad, keeps 16B alignment)
#define DEPTH 4     // register prefetch depth (64 % DEPTH == 0, DEPTH even)
__global__ __launch_bounds__(512) void gemm_copy_kernel(const short* __restrict__ A,
                                                        const float* __restrict__ Em,
                                                        float* __restrict__ sims,
                                                        float* __restrict__ out_em) {
  __shared__ __align__(16) short As[2][Bn * SA];   // 2 x 20480 B
  __shared__ __align__(16) short Bs[2][64 * SA];   // 2 x  5120 B   (total 51200 B)
  const int tid = threadIdx.x;
  const int nbase = blockIdx.x * 64;
  const int lane = tid & 63;
  const int w = tid >> 6, wm = w & 3, wn = w >> 2;
  const int lr = lane & 15, lq = lane >> 4;

  f32x4 acc[4][2];
#pragma unroll
  for (int mi = 0; mi < 4; ++mi)
#pragma unroll
    for (int ni = 0; ni < 2; ++ni) acc[mi][ni] = (f32x4)(0.0f);

  // staging maps
  const int arow0 = tid >> 2, achk = (tid & 3) * 8;        // A: 1024 x 16B chunks, 2/thread
  const int brow = tid >> 3, bcol = (tid & 7) * 4;         // B: 64 rows x 32 f32, 4 f32/thread
  const size_t bgo_base = (size_t)(nbase + brow) * Dk + bcol;

  // prologue: fill the register queue with tiles 0..DEPTH-1
  uint4 aQ[DEPTH][2];
  float4 bQ[DEPTH];
#pragma unroll
  for (int d = 0; d < DEPTH; ++d) {
    const short* ap = A + (size_t)d * (Bn * 32);
    aQ[d][0] = *(const uint4*)(ap + tid * 8);
    aQ[d][1] = *(const uint4*)(ap + (tid + 512) * 8);
    bQ[d] = *(const float4*)(Em + bgo_base + (size_t)d * 32);
  }

  for (int kt0 = 0; kt0 < 64; kt0 += DEPTH) {
#pragma unroll
    for (int d = 0; d < DEPTH; ++d) {
      const int kt = kt0 + d;
      short* as = As[d & 1];   // kt0 % 2 == 0, so kt&1 == d&1 (static)
      short* bs = Bs[d & 1];
      // ---- LDS write of tile kt from queue slot d (waitcnt only for this slot's loads)
      *(uint4*)(as + arow0 * SA + achk) = aQ[d][0];
      *(uint4*)(as + (arow0 + 128) * SA + achk) = aQ[d][1];
      short4 hb;
      hb.x = f2bf(bQ[d].x); hb.y = f2bf(bQ[d].y); hb.z = f2bf(bQ[d].z); hb.w = f2bf(bQ[d].w);
      *(short4*)(bs + brow * SA + bcol) = hb;
      // ---- fused copy-out of em (base is 4B-misaligned vs 16B: dword stores)
      {
        size_t go = bgo_base + (size_t)kt * 32;
        out_em[go + 0] = bQ[d].x;
        out_em[go + 1] = bQ[d].y;
        out_em[go + 2] = bQ[d].z;
        out_em[go + 3] = bQ[d].w;
      }
      // ---- refill slot d with tile kt+DEPTH (stays in flight across barriers)
      if (kt + DEPTH < 64) {
        const short* ap = A + (size_t)(kt + DEPTH) * (Bn * 32);
        aQ[d][0] = *(const uint4*)(ap + tid * 8);
        aQ[d][1] = *(const uint4*)(ap + (tid + 512) * 8);
        bQ[d] = *(const float4*)(Em + bgo_base + (size_t)(kt + DEPTH) * 32);
      }
      __syncthreads();
      // ---- compute on current buffer: wave covers 64(m) x 32(n)
      bf16x8 af[4], bfr[2];
#pragma unroll
      for (int mi = 0; mi < 4; ++mi)
        af[mi] = *(const bf16x8*)(as + (wm * 64 + mi * 16 + lr) * SA + lq * 8);
#pragma unroll
      for (int ni = 0; ni < 2; ++ni)
        bfr[ni] = *(const bf16x8*)(bs + (wn * 32 + ni * 16 + lr) * SA + lq * 8);
#pragma unroll
      for (int mi = 0; mi < 4; ++mi)
#pragma unroll
        for (int ni = 0; ni < 2; ++ni)
          acc[mi][ni] = __builtin_amdgcn_mfma_f32_16x16x32_bf16(af[mi], bfr[ni], acc[mi][ni], 0, 0, 0);
      // single barrier per iter is safe: the barrier at iter k+1 separates
      // compute(k) on buf k&1 from the ds_write at iter k+2 that reuses it
    }
  }
  // ---- epilogue
#pragma unroll
  for (int mi = 0; mi < 4; ++mi)
#pragma unroll
    for (int ni = 0; ni < 2; ++ni)
#pragma unroll
      for (int r = 0; r < 4; ++r) {
        int m = wm * 64 + mi * 16 + lq * 4 + r;
        int n = nbase + wn * 32 + ni * 16 + lr;
        sims[(size_t)m * Nn + n] = acc[mi][ni][r];
      }
}

// ---------------------------------------------------------------- block reduction helpers (256 threads; LDS ptr non-volatile,
// ordering provided by __syncthreads; volatile generic ptrs hit a gfx950 backend bug)
__device__ inline float blockRedSumF(float v, float* red, int tid) {
#pragma unroll
  for (int off = 32; off; off >>= 1) v += __shfl_down(v, off, 64);
  if ((tid & 63) == 0) red[tid >> 6] = v;
  __syncthreads();
  float r = red[0] + red[1] + red[2] + red[3];
  __syncthreads();
  return r;
}
__device__ inline int blockRedSumI(int v, int* red, int tid) {
#pragma unroll
  for (int off = 32; off; off >>= 1) v += __shfl_down(v, off, 64);
  if ((tid & 63) == 0) red[tid >> 6] = v;
  __syncthreads();
  int r = red[0] + red[1] + red[2] + red[3];
  __syncthreads();
  return r;
}
__device__ inline float blockRedMaxF(float v, float* red, int tid) {
#pragma unroll
  for (int off = 32; off; off >>= 1) v = fmaxf(v, __shfl_down(v, off, 64));
  if ((tid & 63) == 0) red[tid >> 6] = v;
  __syncthreads();
  float r = fmaxf(fmaxf(red[0], red[1]), fmaxf(red[2], red[3]));
  __syncthreads();
  return r;
}
__device__ inline unsigned blockRedMaxU(unsigned v, unsigned* red, int tid) {
#pragma unroll
  for (int off = 32; off; off >>= 1) { unsigned o = __shfl_down(v, off, 64); v = o > v ? o : v; }
  if ((tid & 63) == 0) red[tid >> 6] = v;
  __syncthreads();
  unsigned r = red[0];
  r = red[1] > r ? red[1] : r; r = red[2] > r ? red[2] : r; r = red[3] > r ? red[3] : r;
  __syncthreads();
  return r;
}

// ---------------------------------------------------------------- loss: one block (256 thr) per sample row
// row held in registers (ordered-uint form); exact top-50 via 32-round bit bisection for v50
__global__ __launch_bounds__(256) void loss_kernel(const float* __restrict__ sims,
                                                   const int* __restrict__ targets,
                                                   const int* __restrict__ cams,
                                                   const int* __restrict__ cnt,
                                                   const int* __restrict__ epoch,
                                                   float* __restrict__ lossPartial) {
  __shared__ float redf[4];
  __shared__ int redi[4];
  __shared__ unsigned redu[4];
  __shared__ unsigned pordS[Cc];
  const int b = blockIdx.x, t = threadIdx.x;

  // load row: thread t holds elements (q*256+t)*4+s, q=0..15, s=0..3
  uint4 uarr[16];
  {
    const float4* src = (const float4*)(sims + (size_t)b * Nn);
#pragma unroll
    for (int q = 0; q < 16; ++q) {
      float4 v = src[q * 256 + t];
      uarr[q].x = f2ord(v.x); uarr[q].y = f2ord(v.y);
      uarr[q].z = f2ord(v.z); uarr[q].w = f2ord(v.w);
    }
  }
  const int cam = cams[b], tgt = targets[b];
  const int cg = cnt[cam];
  const float invc = 1.0f / (float)(cg > 0 ? cg : 1);

  // ---- positives p_c = tgt + 2048c: all owned by thread (tgt>>2)&255
  {
    const int owner = (tgt >> 2) & 255;
    if (t == owner) {
      const int slot = tgt & 3;
#pragma unroll
      for (int c = 0; c < Cc; ++c) {
        const int chunk = (tgt >> 10) + 2 * c;
        uint4 uc = uarr[0];
#pragma unroll
        for (int q = 1; q < 16; ++q)
          if (chunk == q) uc = uarr[q];
        unsigned po = uc.x;
        if (slot == 1) po = uc.y;
        else if (slot == 2) po = uc.z;
        else if (slot == 3) po = uc.w;
        pordS[c] = po;
      }
    }
  }
  __syncthreads();
  unsigned pord[Cc];
  float pv[Cc];
#pragma unroll
  for (int c = 0; c < Cc; ++c) { pord[c] = pordS[c]; pv[c] = ord2f(pord[c]); }

  // ---- intra-camera CE: camera block = chunks {2cam, 2cam+1} (8 values/thread)
  float cv[8];
  {
    uint4 u0 = uarr[0], u1 = uarr[1];
#pragma unroll
    for (int q = 0; q < 16; ++q) {
      if (2 * cam == q) u0 = uarr[q];
      if (2 * cam + 1 == q) u1 = uarr[q];
    }
    cv[0] = ord2f(u0.x); cv[1] = ord2f(u0.y); cv[2] = ord2f(u0.z); cv[3] = ord2f(u0.w);
    cv[4] = ord2f(u1.x); cv[5] = ord2f(u1.y); cv[6] = ord2f(u1.z); cv[7] = ord2f(u1.w);
  }
  float lm = cv[0];
#pragma unroll
  for (int k = 1; k < 8; ++k) lm = fmaxf(lm, cv[k]);
  const float maxv = blockRedMaxF(lm, redf, t);
  float ls = 0.0f;
#pragma unroll
  for (int k = 0; k < 8; ++k) ls += __expf((cv[k] - maxv) * INV_T);
  const float sumexp = blockRedSumF(ls, redf, t);
  float total = (__logf(sumexp) + (maxv - pv[cam]) * INV_T) * invc;

  if (*epoch >= 5) {
    // ---- exact 50th-largest of the masked multiset (positives excluded by count subtraction)
    unsigned cur = 0u;
#pragma unroll 1
    for (int bit = 31; bit >= 0; --bit) {
      const unsigned cand = cur | (1u << bit);
      int c = 0;
#pragma unroll
      for (int q = 0; q < 16; ++q)
        c += (uarr[q].x >= cand) + (uarr[q].y >= cand) + (uarr[q].z >= cand) + (uarr[q].w >= cand);
      int ctot = blockRedSumI(c, redi, t);
#pragma unroll
      for (int cc2 = 0; cc2 < Cc; ++cc2) ctot -= (pord[cc2] >= cand);
      if (ctot >= BG) cur = cand;
    }
    // strictly-greater count (for tie multiplicity at v50)
    int cg2 = 0;
#pragma unroll
    for (int q = 0; q < 16; ++q)
      cg2 += (uarr[q].x > cur) + (uarr[q].y > cur) + (uarr[q].z > cur) + (uarr[q].w > cur);
    int cgt = blockRedSumI(cg2, redi, t);
#pragma unroll
    for (int cc2 = 0; cc2 < Cc; ++cc2) cgt -= (pord[cc2] > cur);
    // stability shift m = row max (== max of cat candidates)
    unsigned um = 0u;
#pragma unroll
    for (int q = 0; q < 16; ++q) {
      um = uarr[q].x > um ? uarr[q].x : um;
      um = uarr[q].y > um ? uarr[q].y : um;
      um = uarr[q].z > um ? uarr[q].z : um;
      um = uarr[q].w > um ? uarr[q].w : um;
    }
    const unsigned umax = blockRedMaxU(um, redu, t);
    const float m = ord2f(umax);
    const float v50 = ord2f(cur);
    // sum of exp over top-50 masked + positives
    float s = 0.0f;
#pragma unroll
    for (int q = 0; q < 16; ++q) {
      if (uarr[q].x > cur) s += __expf((ord2f(uarr[q].x) - m) * INV_T);
      if (uarr[q].y > cur) s += __expf((ord2f(uarr[q].y) - m) * INV_T);
      if (uarr[q].z > cur) s += __expf((ord2f(uarr[q].z) - m) * INV_T);
      if (uarr[q].w > cur) s += __expf((ord2f(uarr[q].w) - m) * INV_T);
    }
    float S = blockRedSumF(s, redf, t);
    float psum = 0.0f;
#pragma unroll
    for (int cc2 = 0; cc2 < Cc; ++cc2) {
      if (pord[cc2] > cur) S -= __expf((pv[cc2] - m) * INV_T);   // remove positives from >v50 set
      S += __expf((pv[cc2] - m) * INV_T);                        // add all positives (cat)
      psum += pv[cc2];
    }
    S += (float)(BG - cgt) * __expf((v50 - m) * INV_T);          // ties at v50
    const float lse = m * INV_T + __logf(S);
    const float al = lse - psum * (INV_T / 8.0f);
    total += 0.5f * al * invc;
  }
  if (t == 0) lossPartial[b] = total;
}

// ---------------------------------------------------------------- finalize: sum 256 partials -> loss
__global__ __launch_bounds__(256) void finalize_kernel(const float* __restrict__ lossPartial,
                                                       float* __restrict__ loss) {
  __shared__ float redf[4];
  const int t = threadIdx.x;
  float v = lossPartial[t];
  const float r = blockRedSumF(v, redf, t);
  if (t == 0) loss[0] = r;
}

// ---------------------------------------------------------------- EMA scatter update + renorm
__global__ __launch_bounds__(256) void ema_kernel(const float* __restrict__ em,
                                                  const float* __restrict__ inputs,
                                                  const int* __restrict__ rowArr,
                                                  const int* __restrict__ first,
                                                  float* __restrict__ out_em) {
  const int b = blockIdx.x, tid = threadIdx.x;
  if (!first[b]) return;   // uniform per block
  const int r = rowArr[b];
  __shared__ int rows[Bn];
  __shared__ float red[4];
  rows[tid] = rowArr[tid];
  __syncthreads();
  float v[8];
#pragma unroll
  for (int u = 0; u < 8; ++u) v[u] = em[(size_t)r * Dk + u * 256 + tid];
  const int lane = tid & 63, w = tid >> 6;
  for (int j = b; j < Bn; ++j) {
    if (rows[j] != r) continue;   // uniform
#pragma unroll
    for (int u = 0; u < 8; ++u)
      v[u] = 0.2f * v[u] + 0.8f * inputs[(size_t)j * Dk + u * 256 + tid];
    float ss = 0.0f;
#pragma unroll
    for (int u = 0; u < 8; ++u) ss += v[u] * v[u];
#pragma unroll
    for (int off = 32; off; off >>= 1) ss += __shfl_down(ss, off, 64);
    if (lane == 0) red[w] = ss;
    __syncthreads();
    const float inv = 1.0f / sqrtf(red[0] + red[1] + red[2] + red[3]);
#pragma unroll
    for (int u = 0; u < 8; ++u) v[u] *= inv;
    __syncthreads();
  }
#pragma unroll
  for (int u = 0; u < 8; ++u) out_em[(size_t)r * Dk + u * 256 + tid] = v[u];
}

// ---------------------------------------------------------------- launch
extern "C" void kernel_launch(void* const* d_in, const int* in_sizes, int n_in,
                              void* d_out, int out_size, void* d_ws, size_t ws_size,
                              hipStream_t stream) {
  const float* inputs  = (const float*)d_in[0];
  const float* em      = (const float*)d_in[1];
  const int*   targets = (const int*)d_in[2];
  const int*   cams    = (const int*)d_in[3];
  const int*   epoch   = (const int*)d_in[4];
  float* loss   = (float*)d_out;
  float* out_em = (float*)d_out + 1;

  float* sims = (float*)d_ws;                                          // 16 MB
  short* a16  = (short*)((char*)d_ws + (size_t)Bn * Nn * 4);           // 1 MB packed A
  float* lossPartial = (float*)((char*)d_ws + (size_t)Bn * Nn * 4 + (size_t)Bn * Dk * 2);
  int* ibase  = (int*)(lossPartial + Bn);
  int* cnt    = ibase;
  int* rowArr = ibase + 8;
  int* first  = ibase + 8 + Bn;

  hipLaunchKernelGGL(prep_kernel,    dim3(1),       dim3(256), 0, stream, cams, targets, cnt, rowArr, first);
  hipLaunchKernelGGL(convert_kernel, dim3(512),     dim3(256), 0, stream, inputs, a16, Bn * Dk / 4);
  hipLaunchKernelGGL(gemm_copy_kernel, dim3(Nn / 64), dim3(512), 0, stream, a16, em, sims, out_em);
  hipLaunchKernelGGL(loss_kernel,    dim3(Bn),      dim3(256), 0, stream, sims, targets, cams, cnt, epoch, lossPartial);
  hipLaunchKernelGGL(finalize_kernel, dim3(1),      dim3(256), 0, stream, lossPartial, loss);
  hipLaunchKernelGGL(ema_kernel,     dim3(Bn),      dim3(256), 0, stream, em, inputs, rowArr, first, out_em);
}

// Round 4
// 407.764 us; speedup vs baseline: 1.1263x; 1.1263x over previous
//
#include <hip/hip_runtime.h>

#define Bn 256
#define Dk 2048
#define Cc 8
#define Mm 2048
#define Nn 16384
#define BG 50
#define INV_T 20.0f

typedef __attribute__((ext_vector_type(8))) short bf16x8;
typedef __attribute__((ext_vector_type(4))) float f32x4;

__device__ inline short f2bf(float f) {
  unsigned u = __builtin_bit_cast(unsigned, f);
  u = (u + 0x7fffu + ((u >> 16) & 1u)) >> 16;   // RNE, inputs finite
  return (short)u;
}
// order-isomorphic mapping float -> uint (monotone for all finite values)
__device__ inline unsigned f2ord(float f) {
  unsigned u = __builtin_bit_cast(unsigned, f);
  return (u & 0x80000000u) ? ~u : (u | 0x80000000u);
}
__device__ inline float ord2f(unsigned o) {
  unsigned u = (o & 0x80000000u) ? (o ^ 0x80000000u) : ~o;
  return __builtin_bit_cast(float, u);
}

// ---------------------------------------------------------------- prep: cam histogram, first-occurrence flags
__global__ __launch_bounds__(256) void prep_kernel(const int* __restrict__ cams,
                                                   const int* __restrict__ targets,
                                                   int* __restrict__ cnt,
                                                   int* __restrict__ rowArr,
                                                   int* __restrict__ first) {
  __shared__ int rs[Bn];
  __shared__ int lc[Cc];
  const int t = threadIdx.x;
  const int r = cams[t] * Mm + targets[t];
  rs[t] = r;
  if (t < Cc) lc[t] = 0;
  __syncthreads();
  atomicAdd(&lc[cams[t]], 1);
  __syncthreads();
  if (t < Cc) cnt[t] = lc[t];
  int fst = 1;
  for (int j = 0; j < t; ++j)
    if (rs[j] == r) fst = 0;
  rowArr[t] = r;
  first[t] = fst;
}

// ---------------------------------------------------------------- convert+pack A: f32 -> bf16, per-K-tile (BK=32) layout
// aPack[kt][row][k] : kt in [0,64), row in [0,256), k in [0,32)
// This IS the MFMA A-fragment layout: a wave's fragment load is 1KB contiguous.
__global__ __launch_bounds__(256) void convert_kernel(const float* __restrict__ x,
                                                      short* __restrict__ a, int n4) {
  int i = blockIdx.x * 256 + threadIdx.x;
  if (i >= n4) return;
  float4 v = ((const float4*)x)[i];
  int row = i >> 9, j = i & 511;          // 512 float4 per row
  int kt = j >> 3, off = (j & 7) * 4;     // 8 float4 per K-tile of 32
  short4 h;
  h.x = f2bf(v.x); h.y = f2bf(v.y); h.z = f2bf(v.z); h.w = f2bf(v.w);
  *(short4*)(a + (size_t)kt * (Bn * 32) + row * 32 + off) = h;
}

// ---------------------------------------------------------------- GEMM sims = A @ em^T, fused em copy-out
// BM=256, BN=64, BK=32, 512 threads (8 waves = 4m x 2n), grid 256.
// NO LDS, NO BARRIERS. Rationale: any __syncthreads() forces the compiler to
// emit s_waitcnt vmcnt(0) before s_barrier, draining all in-flight loads and
// latency-serializing the K-loop (rounds 0/1). Here each wave reads its A
// fragments directly from the packed bf16 A buffer (1KB contiguous per wave
// per tile, L2-resident) and its B fragments directly from Em (full 128B
// lines), converting f32->bf16 in-register. 8 barrier-free waves/CU keep
// ~72KB/CU of reads in flight -- well above the ~10KB/CU latency-BW product.
// Per-tile compute is only ~40cy/wave, so TLP (not intra-wave pipelining)
// carries the overlap; #pragma unroll 4 lets the compiler hoist loads across
// iterations with per-register waitcnt for additional ILP.
__global__ __launch_bounds__(512) void gemm_copy_kernel(const short* __restrict__ A,
                                                        const float* __restrict__ Em,
                                                        float* __restrict__ sims,
                                                        float* __restrict__ out_em) {
  const int tid = threadIdx.x;
  const int nbase = blockIdx.x * 64;
  const int lane = tid & 63;
  const int w = tid >> 6, wm = w & 3, wn = w >> 2;
  const int lr = lane & 15, lq = lane >> 4;

  f32x4 acc[4][2];
#pragma unroll
  for (int mi = 0; mi < 4; ++mi)
#pragma unroll
    for (int ni = 0; ni < 2; ++ni) acc[mi][ni] = (f32x4)(0.0f);

  // A fragment base: row = wm*64 + mi*16 + lr, k = lq*8 within tile kt
  const short* aP = A + (wm * 64 + lr) * 32 + lq * 8;
  // B fragment base: Em row nbase + wn*32 + ni*16 + lr, f32 col kt*32 + lq*8
  const float* bP = Em + (size_t)(nbase + wn * 32 + lr) * Dk + lq * 8;
  // copy-out map: row = tid>>3 (of 64), col = (tid&7)*4; 8KB per tile per block
  const int crow = tid >> 3, ccol = (tid & 7) * 4;
  const float* cS = Em + (size_t)(nbase + crow) * Dk + ccol;
  float* cD = out_em + (size_t)(nbase + crow) * Dk + ccol;

#pragma unroll 4
  for (int kt = 0; kt < 64; ++kt) {
    bf16x8 a0 = *(const bf16x8*)(aP + (size_t)kt * 8192);
    bf16x8 a1 = *(const bf16x8*)(aP + (size_t)kt * 8192 + 512);
    bf16x8 a2 = *(const bf16x8*)(aP + (size_t)kt * 8192 + 1024);
    bf16x8 a3 = *(const bf16x8*)(aP + (size_t)kt * 8192 + 1536);
    float4 b00 = *(const float4*)(bP + kt * 32);
    float4 b01 = *(const float4*)(bP + kt * 32 + 4);
    float4 b10 = *(const float4*)(bP + 16 * Dk + kt * 32);
    float4 b11 = *(const float4*)(bP + 16 * Dk + kt * 32 + 4);
    float4 c = *(const float4*)(cS + kt * 32);

    bf16x8 bf0, bf1;
    bf0[0] = f2bf(b00.x); bf0[1] = f2bf(b00.y); bf0[2] = f2bf(b00.z); bf0[3] = f2bf(b00.w);
    bf0[4] = f2bf(b01.x); bf0[5] = f2bf(b01.y); bf0[6] = f2bf(b01.z); bf0[7] = f2bf(b01.w);
    bf1[0] = f2bf(b10.x); bf1[1] = f2bf(b10.y); bf1[2] = f2bf(b10.z); bf1[3] = f2bf(b10.w);
    bf1[4] = f2bf(b11.x); bf1[5] = f2bf(b11.y); bf1[6] = f2bf(b11.z); bf1[7] = f2bf(b11.w);

    acc[0][0] = __builtin_amdgcn_mfma_f32_16x16x32_bf16(a0, bf0, acc[0][0], 0, 0, 0);
    acc[0][1] = __builtin_amdgcn_mfma_f32_16x16x32_bf16(a0, bf1, acc[0][1], 0, 0, 0);
    acc[1][0] = __builtin_amdgcn_mfma_f32_16x16x32_bf16(a1, bf0, acc[1][0], 0, 0, 0);
    acc[1][1] = __builtin_amdgcn_mfma_f32_16x16x32_bf16(a1, bf1, acc[1][1], 0, 0, 0);
    acc[2][0] = __builtin_amdgcn_mfma_f32_16x16x32_bf16(a2, bf0, acc[2][0], 0, 0, 0);
    acc[2][1] = __builtin_amdgcn_mfma_f32_16x16x32_bf16(a2, bf1, acc[2][1], 0, 0, 0);
    acc[3][0] = __builtin_amdgcn_mfma_f32_16x16x32_bf16(a3, bf0, acc[3][0], 0, 0, 0);
    acc[3][1] = __builtin_amdgcn_mfma_f32_16x16x32_bf16(a3, bf1, acc[3][1], 0, 0, 0);

    // fused copy-out of em (out_em base is 4B-misaligned vs 16B: dword stores)
    float* d = cD + kt * 32;
    d[0] = c.x; d[1] = c.y; d[2] = c.z; d[3] = c.w;
  }

  // ---- epilogue
#pragma unroll
  for (int mi = 0; mi < 4; ++mi)
#pragma unroll
    for (int ni = 0; ni < 2; ++ni)
#pragma unroll
      for (int r = 0; r < 4; ++r) {
        int m = wm * 64 + mi * 16 + lq * 4 + r;
        int n = nbase + wn * 32 + ni * 16 + lr;
        sims[(size_t)m * Nn + n] = acc[mi][ni][r];
      }
}

// ---------------------------------------------------------------- block reduction helpers (256 threads; LDS ptr non-volatile,
// ordering provided by __syncthreads; volatile generic ptrs hit a gfx950 backend bug)
__device__ inline float blockRedSumF(float v, float* red, int tid) {
#pragma unroll
  for (int off = 32; off; off >>= 1) v += __shfl_down(v, off, 64);
  if ((tid & 63) == 0) red[tid >> 6] = v;
  __syncthreads();
  float r = red[0] + red[1] + red[2] + red[3];
  __syncthreads();
  return r;
}
__device__ inline int blockRedSumI(int v, int* red, int tid) {
#pragma unroll
  for (int off = 32; off; off >>= 1) v += __shfl_down(v, off, 64);
  if ((tid & 63) == 0) red[tid >> 6] = v;
  __syncthreads();
  int r = red[0] + red[1] + red[2] + red[3];
  __syncthreads();
  return r;
}
__device__ inline float blockRedMaxF(float v, float* red, int tid) {
#pragma unroll
  for (int off = 32; off; off >>= 1) v = fmaxf(v, __shfl_down(v, off, 64));
  if ((tid & 63) == 0) red[tid >> 6] = v;
  __syncthreads();
  float r = fmaxf(fmaxf(red[0], red[1]), fmaxf(red[2], red[3]));
  __syncthreads();
  return r;
}
__device__ inline unsigned blockRedMaxU(unsigned v, unsigned* red, int tid) {
#pragma unroll
  for (int off = 32; off; off >>= 1) { unsigned o = __shfl_down(v, off, 64); v = o > v ? o : v; }
  if ((tid & 63) == 0) red[tid >> 6] = v;
  __syncthreads();
  unsigned r = red[0];
  r = red[1] > r ? red[1] : r; r = red[2] > r ? red[2] : r; r = red[3] > r ? red[3] : r;
  __syncthreads();
  return r;
}

// ---------------------------------------------------------------- loss: one block (256 thr) per sample row
// row held in registers (ordered-uint form); exact top-50 via 32-round bit bisection for v50
__global__ __launch_bounds__(256) void loss_kernel(const float* __restrict__ sims,
                                                   const int* __restrict__ targets,
                                                   const int* __restrict__ cams,
                                                   const int* __restrict__ cnt,
                                                   const int* __restrict__ epoch,
                                                   float* __restrict__ lossPartial) {
  __shared__ float redf[4];
  __shared__ int redi[4];
  __shared__ unsigned redu[4];
  __shared__ unsigned pordS[Cc];
  const int b = blockIdx.x, t = threadIdx.x;

  // load row: thread t holds elements (q*256+t)*4+s, q=0..15, s=0..3
  uint4 uarr[16];
  {
    const float4* src = (const float4*)(sims + (size_t)b * Nn);
#pragma unroll
    for (int q = 0; q < 16; ++q) {
      float4 v = src[q * 256 + t];
      uarr[q].x = f2ord(v.x); uarr[q].y = f2ord(v.y);
      uarr[q].z = f2ord(v.z); uarr[q].w = f2ord(v.w);
    }
  }
  const int cam = cams[b], tgt = targets[b];
  const int cg = cnt[cam];
  const float invc = 1.0f / (float)(cg > 0 ? cg : 1);

  // ---- positives p_c = tgt + 2048c: all owned by thread (tgt>>2)&255
  {
    const int owner = (tgt >> 2) & 255;
    if (t == owner) {
      const int slot = tgt & 3;
#pragma unroll
      for (int c = 0; c < Cc; ++c) {
        const int chunk = (tgt >> 10) + 2 * c;
        uint4 uc = uarr[0];
#pragma unroll
        for (int q = 1; q < 16; ++q)
          if (chunk == q) uc = uarr[q];
        unsigned po = uc.x;
        if (slot == 1) po = uc.y;
        else if (slot == 2) po = uc.z;
        else if (slot == 3) po = uc.w;
        pordS[c] = po;
      }
    }
  }
  __syncthreads();
  unsigned pord[Cc];
  float pv[Cc];
#pragma unroll
  for (int c = 0; c < Cc; ++c) { pord[c] = pordS[c]; pv[c] = ord2f(pord[c]); }

  // ---- intra-camera CE: camera block = chunks {2cam, 2cam+1} (8 values/thread)
  float cv[8];
  {
    uint4 u0 = uarr[0], u1 = uarr[1];
#pragma unroll
    for (int q = 0; q < 16; ++q) {
      if (2 * cam == q) u0 = uarr[q];
      if (2 * cam + 1 == q) u1 = uarr[q];
    }
    cv[0] = ord2f(u0.x); cv[1] = ord2f(u0.y); cv[2] = ord2f(u0.z); cv[3] = ord2f(u0.w);
    cv[4] = ord2f(u1.x); cv[5] = ord2f(u1.y); cv[6] = ord2f(u1.z); cv[7] = ord2f(u1.w);
  }
  float lm = cv[0];
#pragma unroll
  for (int k = 1; k < 8; ++k) lm = fmaxf(lm, cv[k]);
  const float maxv = blockRedMaxF(lm, redf, t);
  float ls = 0.0f;
#pragma unroll
  for (int k = 0; k < 8; ++k) ls += __expf((cv[k] - maxv) * INV_T);
  const float sumexp = blockRedSumF(ls, redf, t);
  float total = (__logf(sumexp) + (maxv - pv[cam]) * INV_T) * invc;

  if (*epoch >= 5) {
    // ---- exact 50th-largest of the masked multiset (positives excluded by count subtraction)
    unsigned cur = 0u;
#pragma unroll 1
    for (int bit = 31; bit >= 0; --bit) {
      const unsigned cand = cur | (1u << bit);
      int c = 0;
#pragma unroll
      for (int q = 0; q < 16; ++q)
        c += (uarr[q].x >= cand) + (uarr[q].y >= cand) + (uarr[q].z >= cand) + (uarr[q].w >= cand);
      int ctot = blockRedSumI(c, redi, t);
#pragma unroll
      for (int cc2 = 0; cc2 < Cc; ++cc2) ctot -= (pord[cc2] >= cand);
      if (ctot >= BG) cur = cand;
    }
    // strictly-greater count (for tie multiplicity at v50)
    int cg2 = 0;
#pragma unroll
    for (int q = 0; q < 16; ++q)
      cg2 += (uarr[q].x > cur) + (uarr[q].y > cur) + (uarr[q].z > cur) + (uarr[q].w > cur);
    int cgt = blockRedSumI(cg2, redi, t);
#pragma unroll
    for (int cc2 = 0; cc2 < Cc; ++cc2) cgt -= (pord[cc2] > cur);
    // stability shift m = row max (== max of cat candidates)
    unsigned um = 0u;
#pragma unroll
    for (int q = 0; q < 16; ++q) {
      um = uarr[q].x > um ? uarr[q].x : um;
      um = uarr[q].y > um ? uarr[q].y : um;
      um = uarr[q].z > um ? uarr[q].z : um;
      um = uarr[q].w > um ? uarr[q].w : um;
    }
    const unsigned umax = blockRedMaxU(um, redu, t);
    const float m = ord2f(umax);
    const float v50 = ord2f(cur);
    // sum of exp over top-50 masked + positives
    float s = 0.0f;
#pragma unroll
    for (int q = 0; q < 16; ++q) {
      if (uarr[q].x > cur) s += __expf((ord2f(uarr[q].x) - m) * INV_T);
      if (uarr[q].y > cur) s += __expf((ord2f(uarr[q].y) - m) * INV_T);
      if (uarr[q].z > cur) s += __expf((ord2f(uarr[q].z) - m) * INV_T);
      if (uarr[q].w > cur) s += __expf((ord2f(uarr[q].w) - m) * INV_T);
    }
    float S = blockRedSumF(s, redf, t);
    float psum = 0.0f;
#pragma unroll
    for (int cc2 = 0; cc2 < Cc; ++cc2) {
      if (pord[cc2] > cur) S -= __expf((pv[cc2] - m) * INV_T);   // remove positives from >v50 set
      S += __expf((pv[cc2] - m) * INV_T);                        // add all positives (cat)
      psum += pv[cc2];
    }
    S += (float)(BG - cgt) * __expf((v50 - m) * INV_T);          // ties at v50
    const float lse = m * INV_T + __logf(S);
    const float al = lse - psum * (INV_T / 8.0f);
    total += 0.5f * al * invc;
  }
  if (t == 0) lossPartial[b] = total;
}

// ---------------------------------------------------------------- finalize: sum 256 partials -> loss
__global__ __launch_bounds__(256) void finalize_kernel(const float* __restrict__ lossPartial,
                                                       float* __restrict__ loss) {
  __shared__ float redf[4];
  const int t = threadIdx.x;
  float v = lossPartial[t];
  const float r = blockRedSumF(v, redf, t);
  if (t == 0) loss[0] = r;
}

// ---------------------------------------------------------------- EMA scatter update + renorm
__global__ __launch_bounds__(256) void ema_kernel(const float* __restrict__ em,
                                                  const float* __restrict__ inputs,
                                                  const int* __restrict__ rowArr,
                                                  const int* __restrict__ first,
                                                  float* __restrict__ out_em) {
  const int b = blockIdx.x, tid = threadIdx.x;
  if (!first[b]) return;   // uniform per block
  const int r = rowArr[b];
  __shared__ int rows[Bn];
  __shared__ float red[4];
  rows[tid] = rowArr[tid];
  __syncthreads();
  float v[8];
#pragma unroll
  for (int u = 0; u < 8; ++u) v[u] = em[(size_t)r * Dk + u * 256 + tid];
  const int lane = tid & 63, w = tid >> 6;
  for (int j = b; j < Bn; ++j) {
    if (rows[j] != r) continue;   // uniform
#pragma unroll
    for (int u = 0; u < 8; ++u)
      v[u] = 0.2f * v[u] + 0.8f * inputs[(size_t)j * Dk + u * 256 + tid];
    float ss = 0.0f;
#pragma unroll
    for (int u = 0; u < 8; ++u) ss += v[u] * v[u];
#pragma unroll
    for (int off = 32; off; off >>= 1) ss += __shfl_down(ss, off, 64);
    if (lane == 0) red[w] = ss;
    __syncthreads();
    const float inv = 1.0f / sqrtf(red[0] + red[1] + red[2] + red[3]);
#pragma unroll
    for (int u = 0; u < 8; ++u) v[u] *= inv;
    __syncthreads();
  }
#pragma unroll
  for (int u = 0; u < 8; ++u) out_em[(size_t)r * Dk + u * 256 + tid] = v[u];
}

// ---------------------------------------------------------------- launch
extern "C" void kernel_launch(void* const* d_in, const int* in_sizes, int n_in,
                              void* d_out, int out_size, void* d_ws, size_t ws_size,
                              hipStream_t stream) {
  const float* inputs  = (const float*)d_in[0];
  const float* em      = (const float*)d_in[1];
  const int*   targets = (const int*)d_in[2];
  const int*   cams    = (const int*)d_in[3];
  const int*   epoch   = (const int*)d_in[4];
  float* loss   = (float*)d_out;
  float* out_em = (float*)d_out + 1;

  float* sims = (float*)d_ws;                                          // 16 MB
  short* a16  = (short*)((char*)d_ws + (size_t)Bn * Nn * 4);           // 1 MB packed A
  float* lossPartial = (float*)((char*)d_ws + (size_t)Bn * Nn * 4 + (size_t)Bn * Dk * 2);
  int* ibase  = (int*)(lossPartial + Bn);
  int* cnt    = ibase;
  int* rowArr = ibase + 8;
  int* first  = ibase + 8 + Bn;

  hipLaunchKernelGGL(prep_kernel,    dim3(1),       dim3(256), 0, stream, cams, targets, cnt, rowArr, first);
  hipLaunchKernelGGL(convert_kernel, dim3(512),     dim3(256), 0, stream, inputs, a16, Bn * Dk / 4);
  hipLaunchKernelGGL(gemm_copy_kernel, dim3(Nn / 64), dim3(512), 0, stream, a16, em, sims, out_em);
  hipLaunchKernelGGL(loss_kernel,    dim3(Bn),      dim3(256), 0, stream, sims, targets, cams, cnt, epoch, lossPartial);
  hipLaunchKernelGGL(finalize_kernel, dim3(1),      dim3(256), 0, stream, lossPartial, loss);
  hipLaunchKernelGGL(ema_kernel,     dim3(Bn),      dim3(256), 0, stream, em, inputs, rowArr, first, out_em);
}